// Round 6
// baseline (177.181 us; speedup 1.0000x reference)
//
#include <hip/hip_runtime.h>

typedef __bf16 bf16;
typedef __attribute__((ext_vector_type(8))) __bf16 bf16x8;
typedef __attribute__((ext_vector_type(4))) __bf16 bf16x4;
typedef __attribute__((ext_vector_type(4))) float floatx4;

#define MFMA16(a, b, c) __builtin_amdgcn_mfma_f32_16x16x32_bf16((a), (b), (c), 0, 0, 0)

// ---------------------------------------------------------------------------
// Kernel 0: W [1024][64] fp32 x3 -> wTf, FRAGMENT-MAJOR bf16:
//   wTf[(((mt*32 + kc)*4 + q)*16 + l)*8 + j] = A[m = mt*16+l][k = kc*32+q*8+j]
//   where A[m][c] = W_{m/64}[c][m%64].
// ---------------------------------------------------------------------------
__global__ void prep_w(const float* __restrict__ Wq, const float* __restrict__ Wk,
                       const float* __restrict__ Wv, bf16* __restrict__ wTf) {
    int tid = blockIdx.x * 256 + threadIdx.x;   // [0, 196608)
    int j = tid & 7;
    int l = (tid >> 3) & 15;
    int q = (tid >> 7) & 3;
    int kc = (tid >> 9) & 31;
    int mt = tid >> 14;                          // 0..11
    int mat = mt >> 2;
    int h = ((mt & 3) << 4) + l;
    int c = kc * 32 + q * 8 + j;
    const float* W = (mat == 0) ? Wq : (mat == 1) ? Wk : Wv;
    wTf[tid] = (bf16)W[c * 64 + h];
}

// ---------------------------------------------------------------------------
// Kernel 1: QKV projection. Block = 256 thr (4 waves) = ONE 16-row t-tile.
// Stage: 16 back-to-back NONTEMPORAL float4 loads per thread (x is read-once;
//   keep L2 for wTf/q/k/vT), convert+store bf16 to LDS (stride 1032).
// Compute: wave w = m-group w (3 m-tiles); A-frags stream from frag-major wTf
//   (L2) with depth-2 register prefetch; B-frag = 1 ds_read_b128/iter.
// 33 KB LDS -> 4 blocks/CU.
// ---------------------------------------------------------------------------
#define XSTR 1032

__global__ __launch_bounds__(256, 4) void proj_qkv(const float* __restrict__ x,
                                                   const bf16* __restrict__ wTf,
                                                   bf16* __restrict__ q,
                                                   bf16* __restrict__ k,
                                                   bf16* __restrict__ vT) {
    __shared__ bf16 xs[16 * XSTR];   // 33 KB

    const int tid = threadIdx.x;
    const int lane = tid & 63;
    const int w = tid >> 6;          // wave 0..3 = m-group
    const int l15 = lane & 15;
    const int quad = lane >> 4;
    const int T0 = blockIdx.x * 16;

    // ---- stage: thread (r = tid>>4, cm = tid&15): 16 nt-loads, then stores
    {
        const int r = tid >> 4;
        const int cm = tid & 15;
        const float* g = x + (size_t)(T0 + r) * 1024 + cm * 8;
        floatx4 f[16];
        #pragma unroll
        for (int c = 0; c < 8; c++) {
            f[2 * c]     = __builtin_nontemporal_load((const floatx4*)(g + c * 128));
            f[2 * c + 1] = __builtin_nontemporal_load((const floatx4*)(g + c * 128 + 4));
        }
        bf16* ld = xs + r * XSTR + cm * 8;
        #pragma unroll
        for (int c = 0; c < 8; c++) {
            bf16x8 pk;
            pk[0] = (bf16)f[2*c][0]; pk[1] = (bf16)f[2*c][1];
            pk[2] = (bf16)f[2*c][2]; pk[3] = (bf16)f[2*c][3];
            pk[4] = (bf16)f[2*c+1][0]; pk[5] = (bf16)f[2*c+1][1];
            pk[6] = (bf16)f[2*c+1][2]; pk[7] = (bf16)f[2*c+1][3];
            *(bf16x8*)(ld + c * 128) = pk;
        }
    }
    __syncthreads();

    // ---- compute: depth-2 A prefetch
    floatx4 acc[3] = {};
    const bf16* aw0 = wTf + (size_t)(w * 3 + 0) * 16384 + lane * 8;
    const bf16* aw1 = wTf + (size_t)(w * 3 + 1) * 16384 + lane * 8;
    const bf16* aw2 = wTf + (size_t)(w * 3 + 2) * 16384 + lane * 8;
    const bf16* xr = xs + l15 * XSTR + quad * 8;

    bf16x8 a0c = *(const bf16x8*)(aw0);
    bf16x8 a1c = *(const bf16x8*)(aw1);
    bf16x8 a2c = *(const bf16x8*)(aw2);
    bf16x8 a0n = *(const bf16x8*)(aw0 + 512);
    bf16x8 a1n = *(const bf16x8*)(aw1 + 512);
    bf16x8 a2n = *(const bf16x8*)(aw2 + 512);

    #pragma unroll 4
    for (int kc = 0; kc < 32; kc++) {
        bf16x8 p0 = *(const bf16x8*)(aw0 + (kc + 2) * 512);  // 4KB slack past end
        bf16x8 p1 = *(const bf16x8*)(aw1 + (kc + 2) * 512);
        bf16x8 p2 = *(const bf16x8*)(aw2 + (kc + 2) * 512);
        bf16x8 bb = *(const bf16x8*)(xr + kc * 32);
        acc[0] = MFMA16(a0c, bb, acc[0]);
        acc[1] = MFMA16(a1c, bb, acc[1]);
        acc[2] = MFMA16(a2c, bb, acc[2]);
        a0c = a0n; a1c = a1n; a2c = a2n;
        a0n = p0;  a1n = p1;  a2n = p2;
    }

    // Epilogue. C-layout: (i,r) -> out-row m = (w*3+i)*16 + quad*4 + r
    // (mat = m/64, h = m%64), out-col t = T0 + l15. q gets 1/8 scale folded.
    const int t = T0 + l15;
    #pragma unroll
    for (int i = 0; i < 3; i++) {
        int mtile = w * 3 + i;
        int mat = mtile >> 2;                          // wave-uniform
        int hbase = ((mtile & 3) << 4) + (quad << 2);
        float sc = (mat == 0) ? 0.125f : 1.0f;
        bf16x4 pk;
        pk[0] = (bf16)(acc[i][0] * sc);
        pk[1] = (bf16)(acc[i][1] * sc);
        pk[2] = (bf16)(acc[i][2] * sc);
        pk[3] = (bf16)(acc[i][3] * sc);
        if (mat == 0) {
            *(bf16x4*)(q + (size_t)t * 64 + hbase) = pk;
        } else if (mat == 1) {
            *(bf16x4*)(k + (size_t)t * 64 + hbase) = pk;
        } else {
            int b = t >> 11, tt = t & 2047;
            #pragma unroll
            for (int r = 0; r < 4; r++)
                vT[(size_t)(b * 64 + hbase + r) * 2048 + tt] = pk[r];
        }
    }
}

// ---------------------------------------------------------------------------
// Kernel 2: causal flash attention, S^T formulation, uniform two-tile blocks,
// SOFTWARE-PIPELINED K: after the S-MFMAs consume kf, the SAME registers are
// immediately reloaded with the next slot's K tile — the ~250-cycle L2 load
// runs under softmax+P-LDS+PV (~700 cyc). Flat slot loop so the prefetch
// crosses the A/B Q-tile boundary. ~116 VGPR under (512,4): no spill.
// ---------------------------------------------------------------------------
#define KP2 72
#define OH 68

__global__ __launch_bounds__(512, 4) void flash(const bf16* __restrict__ q,
                                                const bf16* __restrict__ k,
                                                const bf16* __restrict__ vT,
                                                float* __restrict__ out) {
    __shared__ char smem[8 * 16 * OH * 4];   // union: ps (loop) / Os (merge)
    __shared__ float Ms[8][16], Ls[8][16];
    bf16* psall = (bf16*)smem;
    float* Os = (float*)smem;                // [w][q=16][OH]

    const int b = blockIdx.x & 7;            // batch -> XCD affinity
    const int p = blockIdx.x >> 3;           // 0..63
    const int t0A = p * 16;
    const int t0B = (127 - p) * 16;
    const int nttA = (p >> 2) + 1;
    const int nttB = ((127 - p) >> 2) + 1;
    const int L = nttA + nttB;               // 32..34 for all blocks

    const int tid = threadIdx.x;
    const int w = tid >> 6;
    const int lane = tid & 63;
    const int l15 = lane & 15;
    const int quad = lane >> 4;

    const int s0 = (L * w) >> 3;
    const int s1 = (L * (w + 1)) >> 3;

    const bf16* kbase = k + (size_t)(b * 2048 + l15) * 64 + quad * 8;   // + jt*4096 + mt*1024
    const bf16* vbase = vT + (size_t)(b * 64 + l15) * 2048 + quad * 8;  // + mt*32768 + jt*64 + kc*32
    bf16* psw = psall + w * 16 * KP2;

    // Q B-frags for both tiles (lane l15 = q-row)
    const bf16* qpA = q + (size_t)(b * 2048 + t0A + l15) * 64 + quad * 8;
    const bf16* qpB = q + (size_t)(b * 2048 + t0B + l15) * 64 + quad * 8;
    bf16x8 qfA0 = *(const bf16x8*)qpA;
    bf16x8 qfA1 = *(const bf16x8*)(qpA + 32);
    bf16x8 qfB0 = *(const bf16x8*)qpB;
    bf16x8 qfB1 = *(const bf16x8*)(qpB + 32);

    floatx4 oA[4] = {}, oB[4] = {};
    float miA = -1e30f, liA = 0.f, miB = -1e30f, liB = 0.f;

    // slot -> jt (byte offset into k for this slot's K tile)
    auto jt_of = [&](int s) { return (s < nttA) ? s : (s - nttA); };

    // preload K for slot s0
    bf16x8 kf[8];
    {
        const bf16* kp = kbase + (size_t)jt_of(s0) * 4096;
        #pragma unroll
        for (int mt = 0; mt < 4; mt++) {
            kf[2 * mt]     = *(const bf16x8*)(kp + mt * 1024);
            kf[2 * mt + 1] = *(const bf16x8*)(kp + mt * 1024 + 32);
        }
    }

    for (int s = s0; s < s1; s++) {
        const bool tileA = (s < nttA);
        const int jt = tileA ? s : (s - nttA);
        const int t0v = tileA ? t0A : t0B;
        const bool isdiag = tileA ? (s == nttA - 1) : (s == L - 1);
        bf16x8 qf0 = tileA ? qfA0 : qfB0;
        bf16x8 qf1 = tileA ? qfA1 : qfB1;

        // S^T = K Q^T from prefetched kf
        floatx4 stt[4];
        #pragma unroll
        for (int mt = 0; mt < 4; mt++) {
            floatx4 z = {};
            z = MFMA16(kf[2 * mt], qf0, z);
            z = MFMA16(kf[2 * mt + 1], qf1, z);
            stt[mt] = z;
        }

        // kf consumed -> immediately start next slot's K loads (overlap with
        // softmax + P round-trip + PV below)
        if (s + 1 < s1) {
            const bf16* kp = kbase + (size_t)jt_of(s + 1) * 4096;
            #pragma unroll
            for (int mt = 0; mt < 4; mt++) {
                kf[2 * mt]     = *(const bf16x8*)(kp + mt * 1024);
                kf[2 * mt + 1] = *(const bf16x8*)(kp + mt * 1024 + 32);
            }
        }

        // causal mask (diagonal tile only)
        if (isdiag) {
            #pragma unroll
            for (int mt = 0; mt < 4; mt++)
                #pragma unroll
                for (int r = 0; r < 4; r++) {
                    int kv = jt * 64 + mt * 16 + quad * 4 + r;
                    if (kv > t0v + l15) stt[mt][r] = -1e30f;
                }
        }

        // online softmax: lane-local reduction over 16 vals + 2 shfls
        float mx = fmaxf(fmaxf(fmaxf(stt[0][0], stt[0][1]), fmaxf(stt[0][2], stt[0][3])),
                         fmaxf(fmaxf(stt[1][0], stt[1][1]), fmaxf(stt[1][2], stt[1][3])));
        mx = fmaxf(mx, fmaxf(fmaxf(fmaxf(stt[2][0], stt[2][1]), fmaxf(stt[2][2], stt[2][3])),
                             fmaxf(fmaxf(stt[3][0], stt[3][1]), fmaxf(stt[3][2], stt[3][3]))));
        mx = fmaxf(mx, __shfl_xor(mx, 16, 64));
        mx = fmaxf(mx, __shfl_xor(mx, 32, 64));

        float mi = tileA ? miA : miB;
        float li = tileA ? liA : liB;
        float mnew = fmaxf(mi, mx);
        float aa = __expf(mi - mnew);
        float rs = 0.f;
        #pragma unroll
        for (int mt = 0; mt < 4; mt++)
            #pragma unroll
            for (int r = 0; r < 4; r++) {
                float pv = __expf(stt[mt][r] - mnew);
                stt[mt][r] = pv;
                rs += pv;
            }
        rs += __shfl_xor(rs, 16, 64);
        rs += __shfl_xor(rs, 32, 64);
        if (tileA) { miA = mnew; liA = liA * aa + rs; }
        else       { miB = mnew; liB = liB * aa + rs; }

        floatx4* o = tileA ? oA : oB;
        #pragma unroll
        for (int mt = 0; mt < 4; mt++)
            #pragma unroll
            for (int r = 0; r < 4; r++) o[mt][r] *= aa;

        // P^T: C-layout -> LDS (wave-private) -> B-frag layout
        #pragma unroll
        for (int mt = 0; mt < 4; mt++) {
            bf16x4 pk;
            pk[0] = (bf16)stt[mt][0]; pk[1] = (bf16)stt[mt][1];
            pk[2] = (bf16)stt[mt][2]; pk[3] = (bf16)stt[mt][3];
            *(bf16x4*)(psw + l15 * KP2 + mt * 16 + quad * 4) = pk;
        }

        // O^T += V^T P^T
        const bf16* vp = vbase + jt * 64;
        #pragma unroll
        for (int kc = 0; kc < 2; kc++) {
            bf16x8 pb = *(const bf16x8*)(psw + l15 * KP2 + kc * 32 + quad * 8);
            #pragma unroll
            for (int mt = 0; mt < 4; mt++) {
                bf16x8 va = *(const bf16x8*)(vp + mt * 32768 + kc * 32);
                o[mt] = MFMA16(va, pb, o[mt]);
            }
        }
    }

    // ---- merge tile A then tile B (Os region unions with ps)
    #pragma unroll
    for (int tile = 0; tile < 2; tile++) {
        __syncthreads();
        float mi = tile ? miB : miA;
        float li = tile ? liB : liA;
        if (lane < 16) { Ms[w][lane] = mi; Ls[w][lane] = li; }
        #pragma unroll
        for (int mt = 0; mt < 4; mt++) {
            floatx4 ov = tile ? oB[mt] : oA[mt];
            *(floatx4*)(Os + (w * 16 + l15) * OH + mt * 16 + quad * 4) = ov;
        }
        __syncthreads();
        {
            int qq = tid >> 5;               // 0..15
            int h2 = (tid & 31) * 2;         // 0..62
            float Mg = -1e30f;
            #pragma unroll
            for (int u = 0; u < 8; u++) Mg = fmaxf(Mg, Ms[u][qq]);
            float Lg = 0.f, v0 = 0.f, v1 = 0.f;
            #pragma unroll
            for (int u = 0; u < 8; u++) {
                float sw = __expf(Ms[u][qq] - Mg);
                Lg += sw * Ls[u][qq];
                const float* Or = Os + (u * 16 + qq) * OH + h2;
                v0 += sw * Or[0];
                v1 += sw * Or[1];
            }
            float inv = 1.0f / Lg;
            int t0v = tile ? t0B : t0A;
            float* op = out + (size_t)(b * 2048 + t0v + qq) * 64 + h2;
            __builtin_nontemporal_store(v0 * inv, op);
            __builtin_nontemporal_store(v1 * inv, op + 1);
        }
    }
}

// ---------------------------------------------------------------------------
extern "C" void kernel_launch(void* const* d_in, const int* in_sizes, int n_in,
                              void* d_out, int out_size, void* d_ws, size_t ws_size,
                              hipStream_t stream) {
    const float* x  = (const float*)d_in[0];
    const float* Wq = (const float*)d_in[1];
    const float* Wk = (const float*)d_in[2];
    const float* Wv = (const float*)d_in[3];
    float* out = (float*)d_out;

    char* ws = (char*)d_ws;
    bf16* wTf = (bf16*)ws;                              // 393216 B + 4 KB slack
    bf16* q   = (bf16*)(ws + 397312);                   // 2 MB
    bf16* k   = (bf16*)(ws + 397312 + 2097152);
    bf16* vT  = (bf16*)(ws + 397312 + 2 * 2097152);     // [b*64+h][2048]

    hipLaunchKernelGGL(prep_w,   dim3(768),  dim3(256), 0, stream, Wq, Wk, Wv, wTf);
    hipLaunchKernelGGL(proj_qkv, dim3(1024), dim3(256), 0, stream, x, wTf, q, k, vT);
    hipLaunchKernelGGL(flash,    dim3(512),  dim3(512), 0, stream, q, k, vT, out);
}

// Round 7
// 153.671 us; speedup vs baseline: 1.1530x; 1.1530x over previous
//
#include <hip/hip_runtime.h>

typedef __bf16 bf16;
typedef __attribute__((ext_vector_type(8))) __bf16 bf16x8;
typedef __attribute__((ext_vector_type(4))) __bf16 bf16x4;
typedef __attribute__((ext_vector_type(4))) float floatx4;

#define MFMA16(a, b, c) __builtin_amdgcn_mfma_f32_16x16x32_bf16((a), (b), (c), 0, 0, 0)

// ---------------------------------------------------------------------------
// Kernel 0: W [1024][64] fp32 x3 -> wTf, FRAGMENT-MAJOR bf16:
//   wTf[(((mt*32 + kc)*4 + q)*16 + l)*8 + j] = A[m = mt*16+l][k = kc*32+q*8+j]
//   where A[m][c] = W_{m/64}[c][m%64].
// ---------------------------------------------------------------------------
__global__ void prep_w(const float* __restrict__ Wq, const float* __restrict__ Wk,
                       const float* __restrict__ Wv, bf16* __restrict__ wTf) {
    int tid = blockIdx.x * 256 + threadIdx.x;   // [0, 196608)
    int j = tid & 7;
    int l = (tid >> 3) & 15;
    int q = (tid >> 7) & 3;
    int kc = (tid >> 9) & 31;
    int mt = tid >> 14;                          // 0..11
    int mat = mt >> 2;
    int h = ((mt & 3) << 4) + l;
    int c = kc * 32 + q * 8 + j;
    const float* W = (mat == 0) ? Wq : (mat == 1) ? Wk : Wv;
    wTf[tid] = (bf16)W[c * 64 + h];
}

// ---------------------------------------------------------------------------
// Kernel 1: QKV projection. Block = 256 thr (4 waves) = ONE 16-row t-tile.
// Stage: 16 back-to-back NONTEMPORAL float4 loads per thread (x read-once),
//   convert+store bf16 to LDS (stride 1032). Compute: wave w = m-group w;
//   A-frags stream from frag-major wTf (L2) with depth-2 register prefetch;
//   B-frag = 1 ds_read_b128/iter. 33 KB LDS -> 4 blocks/CU.
// ---------------------------------------------------------------------------
#define XSTR 1032

__global__ __launch_bounds__(256, 4) void proj_qkv(const float* __restrict__ x,
                                                   const bf16* __restrict__ wTf,
                                                   bf16* __restrict__ q,
                                                   bf16* __restrict__ k,
                                                   bf16* __restrict__ vT) {
    __shared__ bf16 xs[16 * XSTR];   // 33 KB

    const int tid = threadIdx.x;
    const int lane = tid & 63;
    const int w = tid >> 6;          // wave 0..3 = m-group
    const int l15 = lane & 15;
    const int quad = lane >> 4;
    const int T0 = blockIdx.x * 16;

    // ---- stage
    {
        const int r = tid >> 4;
        const int cm = tid & 15;
        const float* g = x + (size_t)(T0 + r) * 1024 + cm * 8;
        floatx4 f[16];
        #pragma unroll
        for (int c = 0; c < 8; c++) {
            f[2 * c]     = __builtin_nontemporal_load((const floatx4*)(g + c * 128));
            f[2 * c + 1] = __builtin_nontemporal_load((const floatx4*)(g + c * 128 + 4));
        }
        bf16* ld = xs + r * XSTR + cm * 8;
        #pragma unroll
        for (int c = 0; c < 8; c++) {
            bf16x8 pk;
            pk[0] = (bf16)f[2*c][0]; pk[1] = (bf16)f[2*c][1];
            pk[2] = (bf16)f[2*c][2]; pk[3] = (bf16)f[2*c][3];
            pk[4] = (bf16)f[2*c+1][0]; pk[5] = (bf16)f[2*c+1][1];
            pk[6] = (bf16)f[2*c+1][2]; pk[7] = (bf16)f[2*c+1][3];
            *(bf16x8*)(ld + c * 128) = pk;
        }
    }
    __syncthreads();

    // ---- compute: depth-2 A prefetch
    floatx4 acc[3] = {};
    const bf16* aw0 = wTf + (size_t)(w * 3 + 0) * 16384 + lane * 8;
    const bf16* aw1 = wTf + (size_t)(w * 3 + 1) * 16384 + lane * 8;
    const bf16* aw2 = wTf + (size_t)(w * 3 + 2) * 16384 + lane * 8;
    const bf16* xr = xs + l15 * XSTR + quad * 8;

    bf16x8 a0c = *(const bf16x8*)(aw0);
    bf16x8 a1c = *(const bf16x8*)(aw1);
    bf16x8 a2c = *(const bf16x8*)(aw2);
    bf16x8 a0n = *(const bf16x8*)(aw0 + 512);
    bf16x8 a1n = *(const bf16x8*)(aw1 + 512);
    bf16x8 a2n = *(const bf16x8*)(aw2 + 512);

    #pragma unroll 4
    for (int kc = 0; kc < 32; kc++) {
        bf16x8 p0 = *(const bf16x8*)(aw0 + (kc + 2) * 512);  // 4KB slack past end
        bf16x8 p1 = *(const bf16x8*)(aw1 + (kc + 2) * 512);
        bf16x8 p2 = *(const bf16x8*)(aw2 + (kc + 2) * 512);
        bf16x8 bb = *(const bf16x8*)(xr + kc * 32);
        acc[0] = MFMA16(a0c, bb, acc[0]);
        acc[1] = MFMA16(a1c, bb, acc[1]);
        acc[2] = MFMA16(a2c, bb, acc[2]);
        a0c = a0n; a1c = a1n; a2c = a2n;
        a0n = p0;  a1n = p1;  a2n = p2;
    }

    // Epilogue (C-layout; q gets 1/8 scale folded)
    const int t = T0 + l15;
    #pragma unroll
    for (int i = 0; i < 3; i++) {
        int mtile = w * 3 + i;
        int mat = mtile >> 2;                          // wave-uniform
        int hbase = ((mtile & 3) << 4) + (quad << 2);
        float sc = (mat == 0) ? 0.125f : 1.0f;
        bf16x4 pk;
        pk[0] = (bf16)(acc[i][0] * sc);
        pk[1] = (bf16)(acc[i][1] * sc);
        pk[2] = (bf16)(acc[i][2] * sc);
        pk[3] = (bf16)(acc[i][3] * sc);
        if (mat == 0) {
            *(bf16x4*)(q + (size_t)t * 64 + hbase) = pk;
        } else if (mat == 1) {
            *(bf16x4*)(k + (size_t)t * 64 + hbase) = pk;
        } else {
            int b = t >> 11, tt = t & 2047;
            #pragma unroll
            for (int r = 0; r < 4; r++)
                vT[(size_t)(b * 64 + hbase + r) * 2048 + tt] = pk[r];
        }
    }
}

// ---------------------------------------------------------------------------
// Kernel 2: causal flash attention, S^T formulation, uniform two-tile blocks,
// K software-pipeline via MACRO with DIRECT identifiers (R6's
// `floatx4* o = cond ? oA : oB` demoted the accumulators to scratch -> 65 MB
// spill traffic; never take runtime pointers into register arrays).
// ---------------------------------------------------------------------------
#define KP2 72
#define OH 68

__global__ __launch_bounds__(512, 4) void flash(const bf16* __restrict__ q,
                                                const bf16* __restrict__ k,
                                                const bf16* __restrict__ vT,
                                                float* __restrict__ out) {
    __shared__ char smem[8 * 16 * OH * 4];   // union: ps (loop) / Os (merge)
    __shared__ float Ms[8][16], Ls[8][16];
    bf16* psall = (bf16*)smem;
    float* Os = (float*)smem;                // [w][q=16][OH]

    const int b = blockIdx.x & 7;            // batch -> XCD affinity
    const int p = blockIdx.x >> 3;           // 0..63
    const int t0A = p * 16;
    const int t0B = (127 - p) * 16;
    const int nttA = (p >> 2) + 1;
    const int nttB = ((127 - p) >> 2) + 1;
    const int L = nttA + nttB;               // 32..34 for all blocks

    const int tid = threadIdx.x;
    const int w = tid >> 6;
    const int lane = tid & 63;
    const int l15 = lane & 15;
    const int quad = lane >> 4;

    const int s0 = (L * w) >> 3;
    const int s1 = (L * (w + 1)) >> 3;

    const bf16* kbase = k + (size_t)(b * 2048 + l15) * 64 + quad * 8;   // + jt*4096 + mt*1024
    const bf16* vbase = vT + (size_t)(b * 64 + l15) * 2048 + quad * 8;  // + mt*32768 + jt*64 + kc*32
    bf16* psw = psall + w * 16 * KP2;

    const bf16* qpA = q + (size_t)(b * 2048 + t0A + l15) * 64 + quad * 8;
    const bf16* qpB = q + (size_t)(b * 2048 + t0B + l15) * 64 + quad * 8;
    bf16x8 qfA0 = *(const bf16x8*)qpA;
    bf16x8 qfA1 = *(const bf16x8*)(qpA + 32);
    bf16x8 qfB0 = *(const bf16x8*)qpB;
    bf16x8 qfB1 = *(const bf16x8*)(qpB + 32);

    floatx4 oA[4] = {}, oB[4] = {};
    float miA = -1e30f, liA = 0.f, miB = -1e30f, liB = 0.f;

    // preload K for slot s0 (slot s -> jt = s < nttA ? s : s - nttA)
    bf16x8 kf[8];
    {
        int j0 = (s0 < nttA) ? s0 : (s0 - nttA);
        const bf16* kp = kbase + (size_t)j0 * 4096;
        #pragma unroll
        for (int mt = 0; mt < 4; mt++) {
            kf[2 * mt]     = *(const bf16x8*)(kp + mt * 1024);
            kf[2 * mt + 1] = *(const bf16x8*)(kp + mt * 1024 + 32);
        }
    }

#define KV_STEP(sv, jtv, isdiag, t0v, qf0v, qf1v, mi_, li_, o_)                      \
    {                                                                                 \
        floatx4 stt[4];                                                               \
        _Pragma("unroll") for (int mt = 0; mt < 4; mt++) {                            \
            floatx4 z = {};                                                           \
            z = MFMA16(kf[2 * mt], qf0v, z);                                          \
            z = MFMA16(kf[2 * mt + 1], qf1v, z);                                      \
            stt[mt] = z;                                                              \
        }                                                                             \
        {   /* kf consumed -> prefetch next slot's K under softmax+PV */              \
            int snx = (sv) + 1;                                                       \
            if (snx < s1) {                                                           \
                int jn = (snx < nttA) ? snx : (snx - nttA);                           \
                const bf16* kpn = kbase + (size_t)jn * 4096;                          \
                _Pragma("unroll") for (int mt = 0; mt < 4; mt++) {                    \
                    kf[2 * mt]     = *(const bf16x8*)(kpn + mt * 1024);               \
                    kf[2 * mt + 1] = *(const bf16x8*)(kpn + mt * 1024 + 32);          \
                }                                                                     \
            }                                                                         \
        }                                                                             \
        if (isdiag) {                                                                 \
            _Pragma("unroll") for (int mt = 0; mt < 4; mt++)                          \
                _Pragma("unroll") for (int r = 0; r < 4; r++) {                       \
                    int kv = (jtv) * 64 + mt * 16 + quad * 4 + r;                     \
                    if (kv > (t0v) + l15) stt[mt][r] = -1e30f;                        \
                }                                                                     \
        }                                                                             \
        float mx = fmaxf(fmaxf(fmaxf(stt[0][0], stt[0][1]), fmaxf(stt[0][2], stt[0][3])),  \
                         fmaxf(fmaxf(stt[1][0], stt[1][1]), fmaxf(stt[1][2], stt[1][3]))); \
        mx = fmaxf(mx, fmaxf(fmaxf(fmaxf(stt[2][0], stt[2][1]), fmaxf(stt[2][2], stt[2][3])),  \
                             fmaxf(fmaxf(stt[3][0], stt[3][1]), fmaxf(stt[3][2], stt[3][3])))); \
        mx = fmaxf(mx, __shfl_xor(mx, 16, 64));                                       \
        mx = fmaxf(mx, __shfl_xor(mx, 32, 64));                                       \
        float mnew = fmaxf(mi_, mx);                                                  \
        float aa = __expf(mi_ - mnew);                                                \
        mi_ = mnew;                                                                   \
        float rs = 0.f;                                                               \
        _Pragma("unroll") for (int mt = 0; mt < 4; mt++)                              \
            _Pragma("unroll") for (int r = 0; r < 4; r++) {                           \
                float pv = __expf(stt[mt][r] - mnew);                                 \
                stt[mt][r] = pv;                                                      \
                rs += pv;                                                             \
            }                                                                         \
        rs += __shfl_xor(rs, 16, 64);                                                 \
        rs += __shfl_xor(rs, 32, 64);                                                 \
        li_ = li_ * aa + rs;                                                          \
        _Pragma("unroll") for (int mt = 0; mt < 4; mt++)                              \
            _Pragma("unroll") for (int r = 0; r < 4; r++) o_[mt][r] *= aa;            \
        _Pragma("unroll") for (int mt = 0; mt < 4; mt++) {                            \
            bf16x4 pk;                                                                \
            pk[0] = (bf16)stt[mt][0]; pk[1] = (bf16)stt[mt][1];                       \
            pk[2] = (bf16)stt[mt][2]; pk[3] = (bf16)stt[mt][3];                       \
            *(bf16x4*)(psw + l15 * KP2 + mt * 16 + quad * 4) = pk;                    \
        }                                                                             \
        const bf16* vp = vbase + (jtv) * 64;                                          \
        _Pragma("unroll") for (int kc = 0; kc < 2; kc++) {                            \
            bf16x8 pb = *(const bf16x8*)(psw + l15 * KP2 + kc * 32 + quad * 8);       \
            _Pragma("unroll") for (int mt = 0; mt < 4; mt++) {                        \
                bf16x8 va = *(const bf16x8*)(vp + mt * 32768 + kc * 32);              \
                o_[mt] = MFMA16(va, pb, o_[mt]);                                      \
            }                                                                         \
        }                                                                             \
    }

    // ---- tile A slots: s in [s0, min(s1, nttA)), jt = s
    {
        const int eA = (s1 < nttA) ? s1 : nttA;
        for (int s = s0; s < eA; s++) {
            KV_STEP(s, s, (s == nttA - 1), t0A, qfA0, qfA1, miA, liA, oA);
        }
    }
    // ---- tile B slots: s in [max(s0, nttA), s1), jt = s - nttA
    {
        const int sB = (s0 > nttA) ? s0 : nttA;
        for (int s = sB; s < s1; s++) {
            KV_STEP(s, s - nttA, (s == L - 1), t0B, qfB0, qfB1, miB, liB, oB);
        }
    }
#undef KV_STEP

    // ---- merge tile A then tile B (Os region unions with ps)
    #pragma unroll
    for (int tile = 0; tile < 2; tile++) {
        __syncthreads();
        float mi = tile ? miB : miA;
        float li = tile ? liB : liA;
        if (lane < 16) { Ms[w][lane] = mi; Ls[w][lane] = li; }
        #pragma unroll
        for (int mt = 0; mt < 4; mt++) {
            floatx4 ov = tile ? oB[mt] : oA[mt];
            *(floatx4*)(Os + (w * 16 + l15) * OH + mt * 16 + quad * 4) = ov;
        }
        __syncthreads();
        {
            int qq = tid >> 5;               // 0..15
            int h2 = (tid & 31) * 2;         // 0..62
            float Mg = -1e30f;
            #pragma unroll
            for (int u = 0; u < 8; u++) Mg = fmaxf(Mg, Ms[u][qq]);
            float Lg = 0.f, v0 = 0.f, v1 = 0.f;
            #pragma unroll
            for (int u = 0; u < 8; u++) {
                float sw = __expf(Ms[u][qq] - Mg);
                Lg += sw * Ls[u][qq];
                const float* Or = Os + (u * 16 + qq) * OH + h2;
                v0 += sw * Or[0];
                v1 += sw * Or[1];
            }
            float inv = 1.0f / Lg;
            int t0v = tile ? t0B : t0A;
            float* op = out + (size_t)(b * 2048 + t0v + qq) * 64 + h2;
            __builtin_nontemporal_store(v0 * inv, op);
            __builtin_nontemporal_store(v1 * inv, op + 1);
        }
    }
}

// ---------------------------------------------------------------------------
extern "C" void kernel_launch(void* const* d_in, const int* in_sizes, int n_in,
                              void* d_out, int out_size, void* d_ws, size_t ws_size,
                              hipStream_t stream) {
    const float* x  = (const float*)d_in[0];
    const float* Wq = (const float*)d_in[1];
    const float* Wk = (const float*)d_in[2];
    const float* Wv = (const float*)d_in[3];
    float* out = (float*)d_out;

    char* ws = (char*)d_ws;
    bf16* wTf = (bf16*)ws;                              // 393216 B + 4 KB slack
    bf16* q   = (bf16*)(ws + 397312);                   // 2 MB
    bf16* k   = (bf16*)(ws + 397312 + 2097152);
    bf16* vT  = (bf16*)(ws + 397312 + 2 * 2097152);     // [b*64+h][2048]

    hipLaunchKernelGGL(prep_w,   dim3(768),  dim3(256), 0, stream, Wq, Wk, Wv, wTf);
    hipLaunchKernelGGL(proj_qkv, dim3(1024), dim3(256), 0, stream, x, wTf, q, k, vT);
    hipLaunchKernelGGL(flash,    dim3(512),  dim3(512), 0, stream, q, k, vT, out);
}